// Round 1
// baseline (948.897 us; speedup 1.0000x reference)
//
#include <hip/hip_runtime.h>
#include <cstdint>
#include <cstddef>

#define N 16384
#define NW 256          // N/64 mask words per row
#define HID 16
#define F_IN 64
#define F_OUT 32
#define RCHUNK 8
#define ROWS_PER_CHUNK (N / RCHUNK)   // 2048

// ---------- z = x @ W1  (N x 16) ----------
__global__ void k_xw1(const float* __restrict__ x, const float* __restrict__ W1,
                      float* __restrict__ z) {
  int g = blockIdx.x * 256 + threadIdx.x;      // g < N*16
  int i = g >> 4, c = g & 15;
  const float* xr = x + (size_t)i * F_IN;
  float acc = 0.f;
#pragma unroll
  for (int k = 0; k < F_IN; ++k) acc += xr[k] * W1[k * HID + c];
  z[g] = acc;
}

// ---------- pass 1: column nnz counts + bit-packed mask ----------
__global__ void k_deg_mask(const float* __restrict__ A,
                           unsigned long long* __restrict__ mask,
                           unsigned int* __restrict__ deg) {
  int j = blockIdx.x * 256 + threadIdx.x;      // column
  int w = j >> 6;                              // word index within a row
  int lane = threadIdx.x & 63;
  int i0 = blockIdx.y * 512;
  unsigned int cnt = 0;
#pragma unroll 4
  for (int i = i0; i < i0 + 512; ++i) {
    float a = A[(size_t)i * N + j];
    bool nz = (a != 0.f);
    unsigned long long m = __ballot(nz);
    cnt += nz ? 1u : 0u;
    if (lane == 0) mask[(size_t)i * NW + w] = m;
  }
  atomicAdd(&deg[j], cnt);
}

__global__ void k_deg_only(const float* __restrict__ A,
                           unsigned int* __restrict__ deg) {
  int j = blockIdx.x * 256 + threadIdx.x;
  int i0 = blockIdx.y * 512;
  unsigned int cnt = 0;
#pragma unroll 4
  for (int i = i0; i < i0 + 512; ++i) {
    float a = A[(size_t)i * N + j];
    cnt += (a != 0.f) ? 1u : 0u;
  }
  atomicAdd(&deg[j], cnt);
}

// ---------- dinv + wz[i,c] = dinv[i]*z[i,c] ----------
__global__ void k_dinv_wz(const unsigned int* __restrict__ deg,
                          const float* __restrict__ z,
                          float* __restrict__ dinv, float* __restrict__ wz) {
  int i = blockIdx.x * 256 + threadIdx.x;
  float d = rsqrtf((float)(deg[i] + 1u));      // +1 self-loop
  dinv[i] = d;
  const float4* z4 = (const float4*)(z + (size_t)i * HID);
  float4* w4 = (float4*)(wz + (size_t)i * HID);
#pragma unroll
  for (int q = 0; q < 4; ++q) {
    float4 v = z4[q];
    v.x *= d; v.y *= d; v.z *= d; v.w *= d;
    w4[q] = v;
  }
}

// ---------- s[i] = sum_j A_bin[i,j]*dinv[j]  (one wave per row, mask) ----------
__global__ void k_rowsum_mask(const unsigned long long* __restrict__ mask,
                              const float* __restrict__ dinv,
                              float* __restrict__ s) {
  int wave = threadIdx.x >> 6, lane = threadIdx.x & 63;
  int i = blockIdx.x * 4 + wave;
  float acc = 0.f;
#pragma unroll
  for (int t = 0; t < 4; ++t) {
    int widx = t * 64 + lane;
    unsigned long long wd = mask[(size_t)i * NW + widx];
    int base = widx * 64;
    while (wd) {
      int b = __builtin_ctzll(wd);
      wd &= wd - 1;
      acc += dinv[base + b];
    }
  }
#pragma unroll
  for (int off = 32; off > 0; off >>= 1) acc += __shfl_down(acc, off);
  if (lane == 0) s[i] = acc;
}

__global__ void k_rowsum_direct(const float* __restrict__ A,
                                const float* __restrict__ dinv,
                                float* __restrict__ s) {
  int wave = threadIdx.x >> 6, lane = threadIdx.x & 63;
  int i = blockIdx.x * 4 + wave;
  const float* Ar = A + (size_t)i * N;
  float acc = 0.f;
  for (int t = 0; t < N; t += 64) {
    float a = Ar[t + lane];
    if (a != 0.f) acc += dinv[t + lane];
  }
#pragma unroll
  for (int off = 32; off > 0; off >>= 1) acc += __shfl_down(acc, off);
  if (lane == 0) s[i] = acc;
}

// ---------- SpMM partials: t[j,c] over a row chunk ----------
__global__ void k_spmm_mask(const unsigned long long* __restrict__ mask,
                            const float* __restrict__ wz,
                            float* __restrict__ t_part) {
  int j = blockIdx.x * 256 + threadIdx.x;
  int w = j >> 6;
  int lane = threadIdx.x & 63;
  int i0 = blockIdx.y * ROWS_PER_CHUNK;
  float acc[16];
#pragma unroll
  for (int c = 0; c < 16; ++c) acc[c] = 0.f;
  for (int i = i0; i < i0 + ROWS_PER_CHUNK; ++i) {
    unsigned long long wd = mask[(size_t)i * NW + w];   // wave-uniform
    if (wd == 0ull) continue;
    if ((wd >> lane) & 1ull) {
      const float4* wr = (const float4*)(wz + (size_t)i * HID);
#pragma unroll
      for (int q = 0; q < 4; ++q) {
        float4 v = wr[q];
        acc[q * 4 + 0] += v.x; acc[q * 4 + 1] += v.y;
        acc[q * 4 + 2] += v.z; acc[q * 4 + 3] += v.w;
      }
    }
  }
  float4* tp = (float4*)t_part;
#pragma unroll
  for (int q = 0; q < 4; ++q) {
    float4 v = make_float4(acc[q * 4 + 0], acc[q * 4 + 1],
                           acc[q * 4 + 2], acc[q * 4 + 3]);
    tp[((size_t)blockIdx.y * 4 + q) * N + j] = v;        // coalesced per (chunk,q)
  }
}

__global__ void k_spmm_direct(const float* __restrict__ A,
                              const float* __restrict__ wz,
                              float* __restrict__ t_part) {
  int j = blockIdx.x * 256 + threadIdx.x;
  int i0 = blockIdx.y * ROWS_PER_CHUNK;
  float acc[16];
#pragma unroll
  for (int c = 0; c < 16; ++c) acc[c] = 0.f;
  for (int i = i0; i < i0 + ROWS_PER_CHUNK; ++i) {
    float a = A[(size_t)i * N + j];
    if (a != 0.f) {
      const float4* wr = (const float4*)(wz + (size_t)i * HID);
#pragma unroll
      for (int q = 0; q < 4; ++q) {
        float4 v = wr[q];
        acc[q * 4 + 0] += v.x; acc[q * 4 + 1] += v.y;
        acc[q * 4 + 2] += v.z; acc[q * 4 + 3] += v.w;
      }
    }
  }
  float4* tp = (float4*)t_part;
#pragma unroll
  for (int q = 0; q < 4; ++q) {
    float4 v = make_float4(acc[q * 4 + 0], acc[q * 4 + 1],
                           acc[q * 4 + 2], acc[q * 4 + 3]);
    tp[((size_t)blockIdx.y * 4 + q) * N + j] = v;
  }
}

// ---------- combine partials, h = relu, u partial per block ----------
__global__ void k_combine(const float* __restrict__ t_part,
                          const float* __restrict__ z,
                          const float* __restrict__ dinv,
                          const float* __restrict__ s,
                          const float* __restrict__ b1,
                          float* __restrict__ u_part) {
  int j = blockIdx.x * 256 + threadIdx.x;
  int lane = threadIdx.x & 63, wave = threadIdx.x >> 6;
  const float4* tp = (const float4*)t_part;
  float acc[16];
#pragma unroll
  for (int c = 0; c < 16; ++c) acc[c] = 0.f;
#pragma unroll
  for (int ch = 0; ch < RCHUNK; ++ch) {
#pragma unroll
    for (int q = 0; q < 4; ++q) {
      float4 v = tp[((size_t)ch * 4 + q) * N + j];
      acc[q * 4 + 0] += v.x; acc[q * 4 + 1] += v.y;
      acc[q * 4 + 2] += v.z; acc[q * 4 + 3] += v.w;
    }
  }
  float zz[16];
  const float4* zr = (const float4*)(z + (size_t)j * HID);
#pragma unroll
  for (int q = 0; q < 4; ++q) {
    float4 v = zr[q];
    zz[q * 4 + 0] = v.x; zz[q * 4 + 1] = v.y; zz[q * 4 + 2] = v.z; zz[q * 4 + 3] = v.w;
  }
  float d = dinv[j];
  float rj = d * (d + s[j]);
  float uc[16];
#pragma unroll
  for (int c = 0; c < 16; ++c) {
    float pre = d * (d * zz[c] + acc[c]) + b1[c];
    float h = pre > 0.f ? pre : 0.f;
    uc[c] = rj * h;
  }
#pragma unroll
  for (int c = 0; c < 16; ++c) {
#pragma unroll
    for (int off = 32; off > 0; off >>= 1) uc[c] += __shfl_down(uc[c], off);
  }
  __shared__ float lds[4][16];
  if (lane == 0) {
#pragma unroll
    for (int c = 0; c < 16; ++c) lds[wave][c] = uc[c];
  }
  __syncthreads();
  if (threadIdx.x < 16) {
    float a = lds[0][threadIdx.x] + lds[1][threadIdx.x] +
              lds[2][threadIdx.x] + lds[3][threadIdx.x];
    u_part[blockIdx.x * 16 + threadIdx.x] = a;
  }
}

// ---------- final: u = sum u_part; out = u @ W2 + N*b2 ----------
__global__ void k_final(const float* __restrict__ u_part,
                        const float* __restrict__ W2,
                        const float* __restrict__ b2,
                        float* __restrict__ out) {
  __shared__ float u[16];
  int t = threadIdx.x;
  if (t < 16) {
    float a = 0.f;
    for (int b = 0; b < 64; ++b) a += u_part[b * 16 + t];
    u[t] = a;
  }
  __syncthreads();
  if (t < 32) {
    float o = (float)N * b2[t];
#pragma unroll
    for (int c = 0; c < 16; ++c) o += u[c] * W2[c * F_OUT + t];
    out[t] = o;
  }
}

extern "C" void kernel_launch(void* const* d_in, const int* in_sizes, int n_in,
                              void* d_out, int out_size, void* d_ws, size_t ws_size,
                              hipStream_t stream) {
  const float* A  = (const float*)d_in[0];
  const float* x  = (const float*)d_in[1];
  const float* W1 = (const float*)d_in[2];
  const float* b1 = (const float*)d_in[3];
  const float* W2 = (const float*)d_in[4];
  const float* b2 = (const float*)d_in[5];
  float* out = (float*)d_out;

  char* ws = (char*)d_ws;
  size_t off = 0;
  auto alloc = [&](size_t bytes) {
    char* p = ws + off;
    off += (bytes + 255) & ~(size_t)255;
    return p;
  };

  unsigned int* deg = (unsigned int*)alloc((size_t)N * 4);
  float* dinv       = (float*)alloc((size_t)N * 4);
  float* s          = (float*)alloc((size_t)N * 4);
  float* z          = (float*)alloc((size_t)N * HID * 4);
  float* wz         = (float*)alloc((size_t)N * HID * 4);
  float* u_part     = (float*)alloc(64 * 16 * 4);
  float* t_part     = (float*)alloc((size_t)RCHUNK * N * HID * 4);
  unsigned long long* mask = (unsigned long long*)alloc((size_t)N * NW * 8);
  bool use_mask = (ws_size >= off);   // ~44.2 MB needed for the mask path

  hipMemsetAsync(deg, 0, (size_t)N * 4, stream);
  k_xw1<<<N * HID / 256, 256, 0, stream>>>(x, W1, z);
  if (use_mask) {
    k_deg_mask<<<dim3(64, 32), 256, 0, stream>>>(A, mask, deg);
  } else {
    k_deg_only<<<dim3(64, 32), 256, 0, stream>>>(A, deg);
  }
  k_dinv_wz<<<N / 256, 256, 0, stream>>>(deg, z, dinv, wz);
  if (use_mask) {
    k_rowsum_mask<<<N / 4, 256, 0, stream>>>(mask, dinv, s);
    k_spmm_mask<<<dim3(64, RCHUNK), 256, 0, stream>>>(mask, wz, t_part);
  } else {
    k_rowsum_direct<<<N / 4, 256, 0, stream>>>(A, dinv, s);
    k_spmm_direct<<<dim3(64, RCHUNK), 256, 0, stream>>>(A, wz, t_part);
  }
  k_combine<<<64, 256, 0, stream>>>(t_part, z, dinv, s, b1, u_part);
  k_final<<<1, 64, 0, stream>>>(u_part, W2, b2, out);
}

// Round 2
// 867.489 us; speedup vs baseline: 1.0938x; 1.0938x over previous
//
#include <hip/hip_runtime.h>
#include <cstdint>
#include <cstddef>

#define N 16384
#define NWORDS 256      // N/64 mask words per row
#define HID 16
#define F_IN 64
#define F_OUT 32
#define RCHUNK 8
#define ROWS_PER_CHUNK (N / RCHUNK)   // 2048

// permuted column mapping: word p, bit b  ->  column (p>>2)*256 + 4*b + (p&3)
__device__ __forceinline__ int perm_col(int p, int b) {
  return ((p >> 2) << 8) + (b << 2) + (p & 3);
}

// ---------- z = x @ W1  (N x 16) ----------
__global__ void k_xw1(const float* __restrict__ x, const float* __restrict__ W1,
                      float* __restrict__ z) {
  int g = blockIdx.x * 256 + threadIdx.x;      // g < N*16
  int i = g >> 4, c = g & 15;
  const float4* xr = (const float4*)(x + (size_t)i * F_IN);
  float acc = 0.f;
#pragma unroll
  for (int k4 = 0; k4 < 16; ++k4) {
    float4 v = xr[k4];
    acc += v.x * W1[(4 * k4 + 0) * HID + c];
    acc += v.y * W1[(4 * k4 + 1) * HID + c];
    acc += v.z * W1[(4 * k4 + 2) * HID + c];
    acc += v.w * W1[(4 * k4 + 3) * HID + c];
  }
  z[g] = acc;
}

// ---------- pass 1: row-streaming mask build + column degree ----------
// One wave per row. Lane loads float4 (16B) -> 1KB/instr, sequential 64KB/row.
__global__ void k_mask_deg(const float* __restrict__ A,
                           unsigned long long* __restrict__ mask,
                           unsigned int* __restrict__ deg) {
  int wave = threadIdx.x >> 6, lane = threadIdx.x & 63;
  int i = blockIdx.x * 4 + wave;               // row
  const float4* Ar = (const float4*)(A + (size_t)i * N);
  unsigned long long* mrow = mask + (size_t)i * NWORDS;
#pragma unroll 4
  for (int it = 0; it < 64; ++it) {
    float4 v = Ar[it * 64 + lane];             // columns it*256 + 4*lane + q
    bool n0 = (v.x != 0.f), n1 = (v.y != 0.f), n2 = (v.z != 0.f), n3 = (v.w != 0.f);
    unsigned long long b0 = __ballot(n0);
    unsigned long long b1 = __ballot(n1);
    unsigned long long b2 = __ballot(n2);
    unsigned long long b3 = __ballot(n3);
    if (lane == 0) {
      ulonglong4 m4; m4.x = b0; m4.y = b1; m4.z = b2; m4.w = b3;
      *(ulonglong4*)(mrow + it * 4) = m4;
    }
    int c0 = it * 256 + 4 * lane;
    if (n0) atomicAdd(&deg[c0 + 0], 1u);
    if (n1) atomicAdd(&deg[c0 + 1], 1u);
    if (n2) atomicAdd(&deg[c0 + 2], 1u);
    if (n3) atomicAdd(&deg[c0 + 3], 1u);
  }
}

__global__ void k_deg_only(const float* __restrict__ A,
                           unsigned int* __restrict__ deg) {
  int j = blockIdx.x * 256 + threadIdx.x;
  int i0 = blockIdx.y * 512;
  unsigned int cnt = 0;
#pragma unroll 4
  for (int i = i0; i < i0 + 512; ++i) {
    float a = A[(size_t)i * N + j];
    cnt += (a != 0.f) ? 1u : 0u;
  }
  atomicAdd(&deg[j], cnt);
}

// ---------- dinv + wz[i,c] = dinv[i]*z[i,c] ----------
__global__ void k_dinv_wz(const unsigned int* __restrict__ deg,
                          const float* __restrict__ z,
                          float* __restrict__ dinv, float* __restrict__ wz) {
  int i = blockIdx.x * 256 + threadIdx.x;
  float d = rsqrtf((float)(deg[i] + 1u));      // +1 self-loop
  dinv[i] = d;
  const float4* z4 = (const float4*)(z + (size_t)i * HID);
  float4* w4 = (float4*)(wz + (size_t)i * HID);
#pragma unroll
  for (int q = 0; q < 4; ++q) {
    float4 v = z4[q];
    v.x *= d; v.y *= d; v.z *= d; v.w *= d;
    w4[q] = v;
  }
}

// ---------- s[i] = sum_j A_bin[i,j]*dinv[j]  (one wave per row, mask) ----------
__global__ void k_rowsum_mask(const unsigned long long* __restrict__ mask,
                              const float* __restrict__ dinv,
                              float* __restrict__ s) {
  int wave = threadIdx.x >> 6, lane = threadIdx.x & 63;
  int i = blockIdx.x * 4 + wave;
  float acc = 0.f;
#pragma unroll
  for (int t = 0; t < 4; ++t) {
    int p = t * 64 + lane;
    unsigned long long wd = mask[(size_t)i * NWORDS + p];
    while (wd) {
      int b = __builtin_ctzll(wd);
      wd &= wd - 1;
      acc += dinv[perm_col(p, b)];
    }
  }
#pragma unroll
  for (int off = 32; off > 0; off >>= 1) acc += __shfl_down(acc, off);
  if (lane == 0) s[i] = acc;
}

__global__ void k_rowsum_direct(const float* __restrict__ A,
                                const float* __restrict__ dinv,
                                float* __restrict__ s) {
  int wave = threadIdx.x >> 6, lane = threadIdx.x & 63;
  int i = blockIdx.x * 4 + wave;
  const float* Ar = A + (size_t)i * N;
  float acc = 0.f;
  for (int t = 0; t < N; t += 64) {
    float a = Ar[t + lane];
    if (a != 0.f) acc += dinv[t + lane];
  }
#pragma unroll
  for (int off = 32; off > 0; off >>= 1) acc += __shfl_down(acc, off);
  if (lane == 0) s[i] = acc;
}

// ---------- SpMM partials over a row chunk; output indexed by thread pos t ----------
__global__ void k_spmm_mask(const unsigned long long* __restrict__ mask,
                            const float* __restrict__ wz,
                            float* __restrict__ t_part) {
  int t = blockIdx.x * 256 + threadIdx.x;      // thread position (permuted col)
  int p = t >> 6;                              // wave-uniform word index
  int lane = t & 63;
  int i0 = blockIdx.y * ROWS_PER_CHUNK;
  float acc[16];
#pragma unroll
  for (int c = 0; c < 16; ++c) acc[c] = 0.f;
  for (int i = i0; i < i0 + ROWS_PER_CHUNK; ++i) {
    unsigned long long wd = mask[(size_t)i * NWORDS + p];   // wave-uniform
    if (wd == 0ull) continue;
    if ((wd >> lane) & 1ull) {
      const float4* wr = (const float4*)(wz + (size_t)i * HID);
#pragma unroll
      for (int q = 0; q < 4; ++q) {
        float4 v = wr[q];
        acc[q * 4 + 0] += v.x; acc[q * 4 + 1] += v.y;
        acc[q * 4 + 2] += v.z; acc[q * 4 + 3] += v.w;
      }
    }
  }
  float4* tp = (float4*)t_part;
#pragma unroll
  for (int q = 0; q < 4; ++q) {
    float4 v = make_float4(acc[q * 4 + 0], acc[q * 4 + 1],
                           acc[q * 4 + 2], acc[q * 4 + 3]);
    tp[((size_t)blockIdx.y * 4 + q) * N + t] = v;           // coalesced
  }
}

__global__ void k_spmm_direct(const float* __restrict__ A,
                              const float* __restrict__ wz,
                              float* __restrict__ t_part) {
  int j = blockIdx.x * 256 + threadIdx.x;
  int i0 = blockIdx.y * ROWS_PER_CHUNK;
  float acc[16];
#pragma unroll
  for (int c = 0; c < 16; ++c) acc[c] = 0.f;
  for (int i = i0; i < i0 + ROWS_PER_CHUNK; ++i) {
    float a = A[(size_t)i * N + j];
    if (a != 0.f) {
      const float4* wr = (const float4*)(wz + (size_t)i * HID);
#pragma unroll
      for (int q = 0; q < 4; ++q) {
        float4 v = wr[q];
        acc[q * 4 + 0] += v.x; acc[q * 4 + 1] += v.y;
        acc[q * 4 + 2] += v.z; acc[q * 4 + 3] += v.w;
      }
    }
  }
  float4* tp = (float4*)t_part;
#pragma unroll
  for (int q = 0; q < 4; ++q) {
    float4 v = make_float4(acc[q * 4 + 0], acc[q * 4 + 1],
                           acc[q * 4 + 2], acc[q * 4 + 3]);
    tp[((size_t)blockIdx.y * 4 + q) * N + j] = v;
  }
}

// ---------- combine partials, relu, u partial per block ----------
// perm=1: thread position t maps to column perm_col(t>>6, t&63); perm=0: col=t.
__global__ void k_combine(const float* __restrict__ t_part,
                          const float* __restrict__ z,
                          const float* __restrict__ dinv,
                          const float* __restrict__ s,
                          const float* __restrict__ b1,
                          float* __restrict__ u_part, int perm) {
  int t = blockIdx.x * 256 + threadIdx.x;
  int lane = threadIdx.x & 63, wave = threadIdx.x >> 6;
  int col = perm ? perm_col(t >> 6, t & 63) : t;
  const float4* tp = (const float4*)t_part;
  float acc[16];
#pragma unroll
  for (int c = 0; c < 16; ++c) acc[c] = 0.f;
#pragma unroll
  for (int ch = 0; ch < RCHUNK; ++ch) {
#pragma unroll
    for (int q = 0; q < 4; ++q) {
      float4 v = tp[((size_t)ch * 4 + q) * N + t];
      acc[q * 4 + 0] += v.x; acc[q * 4 + 1] += v.y;
      acc[q * 4 + 2] += v.z; acc[q * 4 + 3] += v.w;
    }
  }
  float zz[16];
  const float4* zr = (const float4*)(z + (size_t)col * HID);
#pragma unroll
  for (int q = 0; q < 4; ++q) {
    float4 v = zr[q];
    zz[q * 4 + 0] = v.x; zz[q * 4 + 1] = v.y; zz[q * 4 + 2] = v.z; zz[q * 4 + 3] = v.w;
  }
  float d = dinv[col];
  float rj = d * (d + s[col]);
  float uc[16];
#pragma unroll
  for (int c = 0; c < 16; ++c) {
    float pre = d * (d * zz[c] + acc[c]) + b1[c];
    float h = pre > 0.f ? pre : 0.f;
    uc[c] = rj * h;
  }
#pragma unroll
  for (int c = 0; c < 16; ++c) {
#pragma unroll
    for (int off = 32; off > 0; off >>= 1) uc[c] += __shfl_down(uc[c], off);
  }
  __shared__ float lds[4][16];
  if (lane == 0) {
#pragma unroll
    for (int c = 0; c < 16; ++c) lds[wave][c] = uc[c];
  }
  __syncthreads();
  if (threadIdx.x < 16) {
    float a = lds[0][threadIdx.x] + lds[1][threadIdx.x] +
              lds[2][threadIdx.x] + lds[3][threadIdx.x];
    u_part[blockIdx.x * 16 + threadIdx.x] = a;
  }
}

// ---------- final: u = sum u_part; out = u @ W2 + N*b2 ----------
__global__ void k_final(const float* __restrict__ u_part,
                        const float* __restrict__ W2,
                        const float* __restrict__ b2,
                        float* __restrict__ out) {
  __shared__ float u[16];
  int t = threadIdx.x;
  if (t < 16) {
    float a = 0.f;
    for (int b = 0; b < 64; ++b) a += u_part[b * 16 + t];
    u[t] = a;
  }
  __syncthreads();
  if (t < 32) {
    float o = (float)N * b2[t];
#pragma unroll
    for (int c = 0; c < 16; ++c) o += u[c] * W2[c * F_OUT + t];
    out[t] = o;
  }
}

extern "C" void kernel_launch(void* const* d_in, const int* in_sizes, int n_in,
                              void* d_out, int out_size, void* d_ws, size_t ws_size,
                              hipStream_t stream) {
  const float* A  = (const float*)d_in[0];
  const float* x  = (const float*)d_in[1];
  const float* W1 = (const float*)d_in[2];
  const float* b1 = (const float*)d_in[3];
  const float* W2 = (const float*)d_in[4];
  const float* b2 = (const float*)d_in[5];
  float* out = (float*)d_out;

  char* ws = (char*)d_ws;
  size_t off = 0;
  auto alloc = [&](size_t bytes) {
    char* p = ws + off;
    off += (bytes + 255) & ~(size_t)255;
    return p;
  };

  unsigned int* deg = (unsigned int*)alloc((size_t)N * 4);
  float* dinv       = (float*)alloc((size_t)N * 4);
  float* s          = (float*)alloc((size_t)N * 4);
  float* z          = (float*)alloc((size_t)N * HID * 4);
  float* wz         = (float*)alloc((size_t)N * HID * 4);
  float* u_part     = (float*)alloc(64 * 16 * 4);
  float* t_part     = (float*)alloc((size_t)RCHUNK * N * HID * 4);
  unsigned long long* mask = (unsigned long long*)alloc((size_t)N * NWORDS * 8);
  bool use_mask = (ws_size >= off);   // ~44.2 MB needed for the mask path

  hipMemsetAsync(deg, 0, (size_t)N * 4, stream);
  k_xw1<<<N * HID / 256, 256, 0, stream>>>(x, W1, z);
  if (use_mask) {
    k_mask_deg<<<N / 4, 256, 0, stream>>>(A, mask, deg);
  } else {
    k_deg_only<<<dim3(64, 32), 256, 0, stream>>>(A, deg);
  }
  k_dinv_wz<<<N / 256, 256, 0, stream>>>(deg, z, dinv, wz);
  if (use_mask) {
    k_rowsum_mask<<<N / 4, 256, 0, stream>>>(mask, dinv, s);
    k_spmm_mask<<<dim3(64, RCHUNK), 256, 0, stream>>>(mask, wz, t_part);
  } else {
    k_rowsum_direct<<<N / 4, 256, 0, stream>>>(A, dinv, s);
    k_spmm_direct<<<dim3(64, RCHUNK), 256, 0, stream>>>(A, wz, t_part);
  }
  k_combine<<<64, 256, 0, stream>>>(t_part, z, dinv, s, b1, u_part, use_mask ? 1 : 0);
  k_final<<<1, 64, 0, stream>>>(u_part, W2, b2, out);
}

// Round 3
// 461.304 us; speedup vs baseline: 2.0570x; 1.8805x over previous
//
#include <hip/hip_runtime.h>
#include <cstdint>
#include <cstddef>

#define N 16384
#define NWORDS 256      // N/64 mask words per row
#define HID 16
#define F_IN 64
#define F_OUT 32
#define RCHUNK 16
#define RPC (N / RCHUNK)     // 1024 rows per chunk
#define PCH 8                // p-chunks for rowsum partials
#define PW (NWORDS / PCH)    // 32 p-words per chunk

// permuted column mapping: word p, bit b  ->  column (p>>2)*256 + 4*b + (p&3)
__device__ __forceinline__ int perm_col(int p, int b) {
  return ((p >> 2) << 8) + (b << 2) + (p & 3);
}

// ---------- z = x @ W1  (N x 16) ----------
__global__ void k_xw1(const float* __restrict__ x, const float* __restrict__ W1,
                      float* __restrict__ z) {
  int g = blockIdx.x * 256 + threadIdx.x;      // g < N*16
  int i = g >> 4, c = g & 15;
  const float4* xr = (const float4*)(x + (size_t)i * F_IN);
  float acc = 0.f;
#pragma unroll
  for (int k4 = 0; k4 < 16; ++k4) {
    float4 v = xr[k4];
    acc += v.x * W1[(4 * k4 + 0) * HID + c];
    acc += v.y * W1[(4 * k4 + 1) * HID + c];
    acc += v.z * W1[(4 * k4 + 2) * HID + c];
    acc += v.w * W1[(4 * k4 + 3) * HID + c];
  }
  z[g] = acc;
}

// ---------- pass 1: row-streaming, deep-batched loads ----------
// One wave per row. 16 float4 loads issued per batch -> 16KB in flight/wave.
// Writes column-major maskT[p*N + row] (4 scattered 8B stores via lanes 0-3)
// and integer column degrees via atomics.
__global__ void k_mask_deg(const float* __restrict__ A,
                           unsigned long long* __restrict__ maskT,
                           unsigned int* __restrict__ deg) {
  int wave = threadIdx.x >> 6, lane = threadIdx.x & 63;
  int i = blockIdx.x * 4 + wave;               // row
  const float4* Ar = (const float4*)(A + (size_t)i * N);
#pragma unroll 1
  for (int b = 0; b < 4; ++b) {
    float4 v[16];
#pragma unroll
    for (int u = 0; u < 16; ++u) v[u] = Ar[(b * 16 + u) * 64 + lane];
#pragma unroll
    for (int u = 0; u < 16; ++u) {
      int it = b * 16 + u;                     // columns it*256 + 4*lane + q
      bool n0 = (v[u].x != 0.f), n1 = (v[u].y != 0.f);
      bool n2 = (v[u].z != 0.f), n3 = (v[u].w != 0.f);
      unsigned long long b0 = __ballot(n0);
      unsigned long long b1 = __ballot(n1);
      unsigned long long b2 = __ballot(n2);
      unsigned long long b3 = __ballot(n3);
      if (lane < 4) {
        unsigned long long bq = (lane == 0) ? b0 : (lane == 1) ? b1
                              : (lane == 2) ? b2 : b3;
        maskT[(size_t)(it * 4 + lane) * N + i] = bq;
      }
      int c0 = it * 256 + 4 * lane;
      if (n0) atomicAdd(&deg[c0 + 0], 1u);
      if (n1) atomicAdd(&deg[c0 + 1], 1u);
      if (n2) atomicAdd(&deg[c0 + 2], 1u);
      if (n3) atomicAdd(&deg[c0 + 3], 1u);
    }
  }
}

__global__ void k_deg_only(const float* __restrict__ A,
                           unsigned int* __restrict__ deg) {
  int j = blockIdx.x * 256 + threadIdx.x;
  int i0 = blockIdx.y * 512;
  unsigned int cnt = 0;
#pragma unroll 4
  for (int i = i0; i < i0 + 512; ++i) {
    float a = A[(size_t)i * N + j];
    cnt += (a != 0.f) ? 1u : 0u;
  }
  atomicAdd(&deg[j], cnt);
}

// ---------- dinv + wz[i,c] = dinv[i]*z[i,c] ----------
__global__ void k_dinv_wz(const unsigned int* __restrict__ deg,
                          const float* __restrict__ z,
                          float* __restrict__ dinv, float* __restrict__ wz) {
  int i = blockIdx.x * 256 + threadIdx.x;
  float d = rsqrtf((float)(deg[i] + 1u));      // +1 self-loop
  dinv[i] = d;
  const float4* z4 = (const float4*)(z + (size_t)i * HID);
  float4* w4 = (float4*)(wz + (size_t)i * HID);
#pragma unroll
  for (int q = 0; q < 4; ++q) {
    float4 v = z4[q];
    v.x *= d; v.y *= d; v.z *= d; v.w *= d;
    w4[q] = v;
  }
}

// ---------- s partials: lane owns a row, iterate a p-chunk coalesced ----------
// s_part[pc*N + i] = sum over p in chunk pc of dinv[cols set in maskT[p][i]]
__global__ void k_rowsum_T(const unsigned long long* __restrict__ maskT,
                           const float* __restrict__ dinv,
                           float* __restrict__ s_part) {
  int wave = threadIdx.x >> 6, lane = threadIdx.x & 63;
  int rg = blockIdx.x >> 1;                    // row group [0,256)
  int pc = (blockIdx.x & 1) * 4 + wave;        // p-chunk [0,8)
  int row = rg * 64 + lane;
  int pbase = pc * PW;
  float acc = 0.f;
#pragma unroll 1
  for (int b = 0; b < PW / 8; ++b) {
    unsigned long long w[8];
#pragma unroll
    for (int u = 0; u < 8; ++u)
      w[u] = maskT[(size_t)(pbase + b * 8 + u) * N + row];
#pragma unroll
    for (int u = 0; u < 8; ++u) {
      int p = pbase + b * 8 + u;
      unsigned long long wd = w[u];
      while (wd) {
        int bb = __builtin_ctzll(wd);
        wd &= wd - 1;
        acc += dinv[perm_col(p, bb)];
      }
    }
  }
  s_part[(size_t)pc * N + row] = acc;
}

__global__ void k_rowsum_direct(const float* __restrict__ A,
                                const float* __restrict__ dinv,
                                float* __restrict__ s) {
  int wave = threadIdx.x >> 6, lane = threadIdx.x & 63;
  int i = blockIdx.x * 4 + wave;
  const float* Ar = A + (size_t)i * N;
  float acc = 0.f;
  for (int t = 0; t < N; t += 64) {
    float a = Ar[t + lane];
    if (a != 0.f) acc += dinv[t + lane];
  }
#pragma unroll
  for (int off = 32; off > 0; off >>= 1) acc += __shfl_down(acc, off);
  if (lane == 0) s[i] = acc;
}

// ---------- SpMM partials: wave owns word-position p, broadcast over rows ----------
__global__ void k_spmm_T(const unsigned long long* __restrict__ maskT,
                         const float* __restrict__ wz,
                         float* __restrict__ t_part) {
  int p = blockIdx.x * 4 + (threadIdx.x >> 6); // word position [0,256)
  int lane = threadIdx.x & 63;
  int i0 = blockIdx.y * RPC;
  const unsigned long long* mcol = maskT + (size_t)p * N + i0;
  float acc[16];
#pragma unroll
  for (int c = 0; c < 16; ++c) acc[c] = 0.f;
  unsigned long long wv = mcol[lane];          // batch 0, coalesced 512B
  for (int batch = 0; batch < RPC / 64; ++batch) {
    unsigned long long wnext = (batch + 1 < RPC / 64)
                             ? mcol[(batch + 1) * 64 + lane] : 0ull;
    int ib = i0 + batch * 64;
    for (int l = 0; l < 64; ++l) {
      unsigned long long wd = __shfl(wv, l);   // uniform word for row ib+l
      if (wd == 0ull) continue;
      if ((wd >> lane) & 1ull) {
        const float4* wr = (const float4*)(wz + (size_t)(ib + l) * HID);
#pragma unroll
        for (int q = 0; q < 4; ++q) {
          float4 v = wr[q];
          acc[q * 4 + 0] += v.x; acc[q * 4 + 1] += v.y;
          acc[q * 4 + 2] += v.z; acc[q * 4 + 3] += v.w;
        }
      }
    }
    wv = wnext;
  }
  int t = blockIdx.x * 256 + threadIdx.x;      // = p*64 + lane
  float4* tp = (float4*)t_part;
#pragma unroll
  for (int q = 0; q < 4; ++q) {
    float4 v = make_float4(acc[q * 4 + 0], acc[q * 4 + 1],
                           acc[q * 4 + 2], acc[q * 4 + 3]);
    tp[((size_t)blockIdx.y * 4 + q) * N + t] = v;   // coalesced
  }
}

__global__ void k_spmm_direct(const float* __restrict__ A,
                              const float* __restrict__ wz,
                              float* __restrict__ t_part) {
  int j = blockIdx.x * 256 + threadIdx.x;
  int i0 = blockIdx.y * RPC;
  float acc[16];
#pragma unroll
  for (int c = 0; c < 16; ++c) acc[c] = 0.f;
  for (int i = i0; i < i0 + RPC; ++i) {
    float a = A[(size_t)i * N + j];
    if (a != 0.f) {
      const float4* wr = (const float4*)(wz + (size_t)i * HID);
#pragma unroll
      for (int q = 0; q < 4; ++q) {
        float4 v = wr[q];
        acc[q * 4 + 0] += v.x; acc[q * 4 + 1] += v.y;
        acc[q * 4 + 2] += v.z; acc[q * 4 + 3] += v.w;
      }
    }
  }
  float4* tp = (float4*)t_part;
#pragma unroll
  for (int q = 0; q < 4; ++q) {
    float4 v = make_float4(acc[q * 4 + 0], acc[q * 4 + 1],
                           acc[q * 4 + 2], acc[q * 4 + 3]);
    tp[((size_t)blockIdx.y * 4 + q) * N + j] = v;
  }
}

// ---------- combine partials, relu, u partial per block ----------
// perm=1: thread position t -> column perm_col(t>>6, t&63); s from 8 partials.
// perm=0: col=t; s read directly.
__global__ void k_combine(const float* __restrict__ t_part,
                          const float* __restrict__ z,
                          const float* __restrict__ dinv,
                          const float* __restrict__ sp,
                          const float* __restrict__ b1,
                          float* __restrict__ u_part, int perm) {
  int t = blockIdx.x * 256 + threadIdx.x;
  int lane = threadIdx.x & 63, wave = threadIdx.x >> 6;
  int col = perm ? perm_col(t >> 6, t & 63) : t;
  const float4* tp = (const float4*)t_part;
  float acc[16];
#pragma unroll
  for (int c = 0; c < 16; ++c) acc[c] = 0.f;
#pragma unroll
  for (int ch = 0; ch < RCHUNK; ++ch) {
#pragma unroll
    for (int q = 0; q < 4; ++q) {
      float4 v = tp[((size_t)ch * 4 + q) * N + t];
      acc[q * 4 + 0] += v.x; acc[q * 4 + 1] += v.y;
      acc[q * 4 + 2] += v.z; acc[q * 4 + 3] += v.w;
    }
  }
  float zz[16];
  const float4* zr = (const float4*)(z + (size_t)col * HID);
#pragma unroll
  for (int q = 0; q < 4; ++q) {
    float4 v = zr[q];
    zz[q * 4 + 0] = v.x; zz[q * 4 + 1] = v.y; zz[q * 4 + 2] = v.z; zz[q * 4 + 3] = v.w;
  }
  float sv;
  if (perm) {
    sv = 0.f;
#pragma unroll
    for (int pc = 0; pc < PCH; ++pc) sv += sp[(size_t)pc * N + col];
  } else {
    sv = sp[col];
  }
  float d = dinv[col];
  float rj = d * (d + sv);
  float uc[16];
#pragma unroll
  for (int c = 0; c < 16; ++c) {
    float pre = d * (d * zz[c] + acc[c]) + b1[c];
    float h = pre > 0.f ? pre : 0.f;
    uc[c] = rj * h;
  }
#pragma unroll
  for (int c = 0; c < 16; ++c) {
#pragma unroll
    for (int off = 32; off > 0; off >>= 1) uc[c] += __shfl_down(uc[c], off);
  }
  __shared__ float lds[4][16];
  if (lane == 0) {
#pragma unroll
    for (int c = 0; c < 16; ++c) lds[wave][c] = uc[c];
  }
  __syncthreads();
  if (threadIdx.x < 16) {
    float a = lds[0][threadIdx.x] + lds[1][threadIdx.x] +
              lds[2][threadIdx.x] + lds[3][threadIdx.x];
    u_part[blockIdx.x * 16 + threadIdx.x] = a;
  }
}

// ---------- final: u = sum u_part; out = u @ W2 + N*b2 ----------
__global__ void k_final(const float* __restrict__ u_part,
                        const float* __restrict__ W2,
                        const float* __restrict__ b2,
                        float* __restrict__ out) {
  __shared__ float u[16];
  int t = threadIdx.x;
  if (t < 16) {
    float a = 0.f;
    for (int b = 0; b < 64; ++b) a += u_part[b * 16 + t];
    u[t] = a;
  }
  __syncthreads();
  if (t < 32) {
    float o = (float)N * b2[t];
#pragma unroll
    for (int c = 0; c < 16; ++c) o += u[c] * W2[c * F_OUT + t];
    out[t] = o;
  }
}

extern "C" void kernel_launch(void* const* d_in, const int* in_sizes, int n_in,
                              void* d_out, int out_size, void* d_ws, size_t ws_size,
                              hipStream_t stream) {
  const float* A  = (const float*)d_in[0];
  const float* x  = (const float*)d_in[1];
  const float* W1 = (const float*)d_in[2];
  const float* b1 = (const float*)d_in[3];
  const float* W2 = (const float*)d_in[4];
  const float* b2 = (const float*)d_in[5];
  float* out = (float*)d_out;

  char* ws = (char*)d_ws;
  size_t off = 0;
  auto alloc = [&](size_t bytes) {
    char* p = ws + off;
    off += (bytes + 255) & ~(size_t)255;
    return p;
  };

  unsigned int* deg = (unsigned int*)alloc((size_t)N * 4);
  float* dinv       = (float*)alloc((size_t)N * 4);
  float* s          = (float*)alloc((size_t)N * 4);
  float* s_part     = (float*)alloc((size_t)PCH * N * 4);
  float* z          = (float*)alloc((size_t)N * HID * 4);
  float* wz         = (float*)alloc((size_t)N * HID * 4);
  float* u_part     = (float*)alloc(64 * 16 * 4);
  float* t_part     = (float*)alloc((size_t)RCHUNK * N * HID * 4);
  unsigned long long* maskT = (unsigned long long*)alloc((size_t)N * NWORDS * 8);
  bool use_mask = (ws_size >= off);   // ~51 MB needed for the mask path

  hipMemsetAsync(deg, 0, (size_t)N * 4, stream);
  k_xw1<<<N * HID / 256, 256, 0, stream>>>(x, W1, z);
  if (use_mask) {
    k_mask_deg<<<N / 4, 256, 0, stream>>>(A, maskT, deg);
  } else {
    k_deg_only<<<dim3(64, 32), 256, 0, stream>>>(A, deg);
  }
  k_dinv_wz<<<N / 256, 256, 0, stream>>>(deg, z, dinv, wz);
  if (use_mask) {
    k_rowsum_T<<<512, 256, 0, stream>>>(maskT, dinv, s_part);
    k_spmm_T<<<dim3(64, RCHUNK), 256, 0, stream>>>(maskT, wz, t_part);
    k_combine<<<64, 256, 0, stream>>>(t_part, z, dinv, s_part, b1, u_part, 1);
  } else {
    k_rowsum_direct<<<N / 4, 256, 0, stream>>>(A, dinv, s);
    k_spmm_direct<<<dim3(64, RCHUNK), 256, 0, stream>>>(A, wz, t_part);
    k_combine<<<64, 256, 0, stream>>>(t_part, z, dinv, s, b1, u_part, 0);
  }
  k_final<<<1, 64, 0, stream>>>(u_part, W2, b2, out);
}

// Round 4
// 377.741 us; speedup vs baseline: 2.5120x; 1.2212x over previous
//
#include <hip/hip_runtime.h>
#include <cstdint>
#include <cstddef>

#define N 16384
#define NWORDS 256      // N/64 mask words per row
#define HID 16
#define F_IN 64
#define F_OUT 32
#define RCHUNK 16
#define RPC (N / RCHUNK)     // 1024 rows per spmm chunk
#define PCH 8                // p-chunks for rowsum partials
#define PW (NWORDS / PCH)    // 32 p-words per chunk
#define RY 16                // row chunks in pass 1
#define ROWCHUNK (N / RY)    // 1024 rows per pass-1 block
#define RPW (ROWCHUNK / 4)   // 256 rows per pass-1 wave
#define NPART (RY * 4)       // 64 deg partials

// permuted column mapping: word p, bit b  ->  column (p>>2)*256 + 4*b + (p&3)
__device__ __forceinline__ int perm_col(int p, int b) {
  return ((p >> 2) << 8) + (b << 2) + (p & 3);
}

__device__ __forceinline__ unsigned long long readlane64(unsigned long long v, int l) {
  union { unsigned long long u; unsigned int s[2]; } x;
  x.u = v;
  unsigned int lo = __builtin_amdgcn_readlane(x.s[0], l);
  unsigned int hi = __builtin_amdgcn_readlane(x.s[1], l);
  return ((unsigned long long)hi << 32) | lo;
}

// ---------- z = x @ W1  (N x 16) ----------
__global__ void k_xw1(const float* __restrict__ x, const float* __restrict__ W1,
                      float* __restrict__ z) {
  int g = blockIdx.x * 256 + threadIdx.x;      // g < N*16
  int i = g >> 4, c = g & 15;
  const float4* xr = (const float4*)(x + (size_t)i * F_IN);
  float acc = 0.f;
#pragma unroll
  for (int k4 = 0; k4 < 16; ++k4) {
    float4 v = xr[k4];
    acc += v.x * W1[(4 * k4 + 0) * HID + c];
    acc += v.y * W1[(4 * k4 + 1) * HID + c];
    acc += v.z * W1[(4 * k4 + 2) * HID + c];
    acc += v.w * W1[(4 * k4 + 3) * HID + c];
  }
  z[g] = acc;
}

// ---------- pass 1: column-block streaming ----------
// Block: 256 columns (jb..jb+255) x ROWCHUNK rows. Wave w: rows r0..r0+RPW.
// Lane loads float4 of its 4 columns -> wave covers 1KB/row, 16-deep batches.
// Degrees in registers (no atomics); mask LDS-staged, flushed column-major
// coalesced. Word p0+q holds columns jb+4*b+q at bit b (= perm_col).
__global__ void k_mask_deg(const float* __restrict__ A,
                           unsigned long long* __restrict__ maskT,
                           unsigned int* __restrict__ deg_part) {
  int wave = threadIdx.x >> 6, lane = threadIdx.x & 63;
  int jb = blockIdx.x * 256;
  int p0 = blockIdx.x * 4;
  int r0 = blockIdx.y * ROWCHUNK + wave * RPW;
  const float* Abase = A + jb + 4 * lane;
  unsigned int cnt0 = 0, cnt1 = 0, cnt2 = 0, cnt3 = 0;
  __shared__ unsigned long long st[4][4][64];   // [wave][q][row in group]
#pragma unroll 1
  for (int rb = 0; rb < RPW; rb += 64) {
#pragma unroll 1
    for (int g = 0; g < 64; g += 16) {
      float4 v[16];
#pragma unroll
      for (int u = 0; u < 16; ++u)
        v[u] = *(const float4*)(Abase + (size_t)(r0 + rb + g + u) * N);
#pragma unroll
      for (int u = 0; u < 16; ++u) {
        bool n0 = (v[u].x != 0.f), n1 = (v[u].y != 0.f);
        bool n2 = (v[u].z != 0.f), n3 = (v[u].w != 0.f);
        unsigned long long b0 = __ballot(n0);
        unsigned long long b1 = __ballot(n1);
        unsigned long long b2 = __ballot(n2);
        unsigned long long b3 = __ballot(n3);
        cnt0 += n0 ? 1u : 0u;  cnt1 += n1 ? 1u : 0u;
        cnt2 += n2 ? 1u : 0u;  cnt3 += n3 ? 1u : 0u;
        if (lane < 4) {
          unsigned long long bq = (lane == 0) ? b0 : (lane == 1) ? b1
                                : (lane == 2) ? b2 : b3;
          st[wave][lane][g + u] = bq;
        }
      }
    }
    // flush 64 rows: 4 coalesced 512B stores (column-major mask)
#pragma unroll
    for (int q = 0; q < 4; ++q)
      maskT[(size_t)(p0 + q) * N + (r0 + rb) + lane] = st[wave][q][lane];
  }
  // degree partials for this wave's row range: uint4 per lane (coalesced)
  int widx = blockIdx.y * 4 + wave;
  uint4 c4; c4.x = cnt0; c4.y = cnt1; c4.z = cnt2; c4.w = cnt3;
  *(uint4*)(deg_part + (size_t)widx * N + jb + 4 * lane) = c4;
}

// fallback (no workspace): column-parallel degree only, atomics
__global__ void k_deg_only(const float* __restrict__ A,
                           unsigned int* __restrict__ deg) {
  int j = blockIdx.x * 256 + threadIdx.x;
  int i0 = blockIdx.y * 512;
  unsigned int cnt = 0;
#pragma unroll 4
  for (int i = i0; i < i0 + 512; ++i) {
    float a = A[(size_t)i * N + j];
    cnt += (a != 0.f) ? 1u : 0u;
  }
  atomicAdd(&deg[j], cnt);
}

// ---------- dinv + wz[i,c] = dinv[i]*z[i,c]; deg = sum of nparts partials ----------
__global__ void k_dinv_wz(const unsigned int* __restrict__ deg_part, int nparts,
                          const float* __restrict__ z,
                          float* __restrict__ dinv, float* __restrict__ wz) {
  int i = blockIdx.x * 256 + threadIdx.x;
  unsigned int dsum = 0;
  for (int w = 0; w < nparts; ++w) dsum += deg_part[(size_t)w * N + i];
  float d = rsqrtf((float)(dsum + 1u));        // +1 self-loop
  dinv[i] = d;
  const float4* z4 = (const float4*)(z + (size_t)i * HID);
  float4* w4 = (float4*)(wz + (size_t)i * HID);
#pragma unroll
  for (int q = 0; q < 4; ++q) {
    float4 v = z4[q];
    v.x *= d; v.y *= d; v.z *= d; v.w *= d;
    w4[q] = v;
  }
}

// ---------- s partials: lane owns a row, iterate a p-chunk coalesced ----------
__global__ void k_rowsum_T(const unsigned long long* __restrict__ maskT,
                           const float* __restrict__ dinv,
                           float* __restrict__ s_part) {
  int wave = threadIdx.x >> 6, lane = threadIdx.x & 63;
  int rg = blockIdx.x >> 1;                    // row group [0,256)
  int pc = (blockIdx.x & 1) * 4 + wave;        // p-chunk [0,8)
  int row = rg * 64 + lane;
  int pbase = pc * PW;
  float acc = 0.f;
#pragma unroll 1
  for (int b = 0; b < PW / 8; ++b) {
    unsigned long long w[8];
#pragma unroll
    for (int u = 0; u < 8; ++u)
      w[u] = maskT[(size_t)(pbase + b * 8 + u) * N + row];
#pragma unroll
    for (int u = 0; u < 8; ++u) {
      int p = pbase + b * 8 + u;
      unsigned long long wd = w[u];
      while (wd) {
        int bb = __builtin_ctzll(wd);
        wd &= wd - 1;
        acc += dinv[perm_col(p, bb)];
      }
    }
  }
  s_part[(size_t)pc * N + row] = acc;
}

__global__ void k_rowsum_direct(const float* __restrict__ A,
                                const float* __restrict__ dinv,
                                float* __restrict__ s) {
  int wave = threadIdx.x >> 6, lane = threadIdx.x & 63;
  int i = blockIdx.x * 4 + wave;
  const float* Ar = A + (size_t)i * N;
  float acc = 0.f;
  for (int t = 0; t < N; t += 64) {
    float a = Ar[t + lane];
    if (a != 0.f) acc += dinv[t + lane];
  }
#pragma unroll
  for (int off = 32; off > 0; off >>= 1) acc += __shfl_down(acc, off);
  if (lane == 0) s[i] = acc;
}

// ---------- SpMM partials: wave owns word-position p; rowmask walk ----------
__global__ void k_spmm_T(const unsigned long long* __restrict__ maskT,
                         const float* __restrict__ wz,
                         float* __restrict__ t_part) {
  int p = blockIdx.x * 4 + (threadIdx.x >> 6); // word position [0,256)
  int lane = threadIdx.x & 63;
  int i0 = blockIdx.y * RPC;
  const unsigned long long* mcol = maskT + (size_t)p * N + i0;
  float acc[16];
#pragma unroll
  for (int c = 0; c < 16; ++c) acc[c] = 0.f;
  unsigned long long wv = mcol[lane];          // batch 0, coalesced 512B
#pragma unroll 1
  for (int batch = 0; batch < RPC / 64; ++batch) {
    unsigned long long wnext = (batch + 1 < RPC / 64)
                             ? mcol[(batch + 1) * 64 + lane] : 0ull;
    int ib = i0 + batch * 64;
    unsigned long long rowmask = __ballot(wv != 0ull);
    while (rowmask) {
      int l = __builtin_ctzll(rowmask);
      rowmask &= rowmask - 1;
      unsigned long long wd = readlane64(wv, l);   // uniform word for row ib+l
      if ((wd >> lane) & 1ull) {
        const float4* wr = (const float4*)(wz + (size_t)(ib + l) * HID);
#pragma unroll
        for (int q = 0; q < 4; ++q) {
          float4 v = wr[q];
          acc[q * 4 + 0] += v.x; acc[q * 4 + 1] += v.y;
          acc[q * 4 + 2] += v.z; acc[q * 4 + 3] += v.w;
        }
      }
    }
    wv = wnext;
  }
  int t = blockIdx.x * 256 + threadIdx.x;      // = p*64 + lane
  float4* tp = (float4*)t_part;
#pragma unroll
  for (int q = 0; q < 4; ++q) {
    float4 v = make_float4(acc[q * 4 + 0], acc[q * 4 + 1],
                           acc[q * 4 + 2], acc[q * 4 + 3]);
    tp[((size_t)blockIdx.y * 4 + q) * N + t] = v;   // coalesced
  }
}

__global__ void k_spmm_direct(const float* __restrict__ A,
                              const float* __restrict__ wz,
                              float* __restrict__ t_part) {
  int j = blockIdx.x * 256 + threadIdx.x;
  int i0 = blockIdx.y * RPC;
  float acc[16];
#pragma unroll
  for (int c = 0; c < 16; ++c) acc[c] = 0.f;
  for (int i = i0; i < i0 + RPC; ++i) {
    float a = A[(size_t)i * N + j];
    if (a != 0.f) {
      const float4* wr = (const float4*)(wz + (size_t)i * HID);
#pragma unroll
      for (int q = 0; q < 4; ++q) {
        float4 v = wr[q];
        acc[q * 4 + 0] += v.x; acc[q * 4 + 1] += v.y;
        acc[q * 4 + 2] += v.z; acc[q * 4 + 3] += v.w;
      }
    }
  }
  float4* tp = (float4*)t_part;
#pragma unroll
  for (int q = 0; q < 4; ++q) {
    float4 v = make_float4(acc[q * 4 + 0], acc[q * 4 + 1],
                           acc[q * 4 + 2], acc[q * 4 + 3]);
    tp[((size_t)blockIdx.y * 4 + q) * N + j] = v;
  }
}

// ---------- combine partials, relu, u partial per block ----------
__global__ void k_combine(const float* __restrict__ t_part,
                          const float* __restrict__ z,
                          const float* __restrict__ dinv,
                          const float* __restrict__ sp,
                          const float* __restrict__ b1,
                          float* __restrict__ u_part, int perm) {
  int t = blockIdx.x * 256 + threadIdx.x;
  int lane = threadIdx.x & 63, wave = threadIdx.x >> 6;
  int col = perm ? perm_col(t >> 6, t & 63) : t;
  const float4* tp = (const float4*)t_part;
  float acc[16];
#pragma unroll
  for (int c = 0; c < 16; ++c) acc[c] = 0.f;
#pragma unroll
  for (int ch = 0; ch < RCHUNK; ++ch) {
#pragma unroll
    for (int q = 0; q < 4; ++q) {
      float4 v = tp[((size_t)ch * 4 + q) * N + t];
      acc[q * 4 + 0] += v.x; acc[q * 4 + 1] += v.y;
      acc[q * 4 + 2] += v.z; acc[q * 4 + 3] += v.w;
    }
  }
  float zz[16];
  const float4* zr = (const float4*)(z + (size_t)col * HID);
#pragma unroll
  for (int q = 0; q < 4; ++q) {
    float4 v = zr[q];
    zz[q * 4 + 0] = v.x; zz[q * 4 + 1] = v.y; zz[q * 4 + 2] = v.z; zz[q * 4 + 3] = v.w;
  }
  float sv;
  if (perm) {
    sv = 0.f;
#pragma unroll
    for (int pc = 0; pc < PCH; ++pc) sv += sp[(size_t)pc * N + col];
  } else {
    sv = sp[col];
  }
  float d = dinv[col];
  float rj = d * (d + sv);
  float uc[16];
#pragma unroll
  for (int c = 0; c < 16; ++c) {
    float pre = d * (d * zz[c] + acc[c]) + b1[c];
    float h = pre > 0.f ? pre : 0.f;
    uc[c] = rj * h;
  }
#pragma unroll
  for (int c = 0; c < 16; ++c) {
#pragma unroll
    for (int off = 32; off > 0; off >>= 1) uc[c] += __shfl_down(uc[c], off);
  }
  __shared__ float lds[4][16];
  if (lane == 0) {
#pragma unroll
    for (int c = 0; c < 16; ++c) lds[wave][c] = uc[c];
  }
  __syncthreads();
  if (threadIdx.x < 16) {
    float a = lds[0][threadIdx.x] + lds[1][threadIdx.x] +
              lds[2][threadIdx.x] + lds[3][threadIdx.x];
    u_part[blockIdx.x * 16 + threadIdx.x] = a;
  }
}

// ---------- final: u = sum u_part; out = u @ W2 + N*b2 ----------
__global__ void k_final(const float* __restrict__ u_part,
                        const float* __restrict__ W2,
                        const float* __restrict__ b2,
                        float* __restrict__ out) {
  __shared__ float u[16];
  int t = threadIdx.x;
  if (t < 16) {
    float a = 0.f;
    for (int b = 0; b < 64; ++b) a += u_part[b * 16 + t];
    u[t] = a;
  }
  __syncthreads();
  if (t < 32) {
    float o = (float)N * b2[t];
#pragma unroll
    for (int c = 0; c < 16; ++c) o += u[c] * W2[c * F_OUT + t];
    out[t] = o;
  }
}

extern "C" void kernel_launch(void* const* d_in, const int* in_sizes, int n_in,
                              void* d_out, int out_size, void* d_ws, size_t ws_size,
                              hipStream_t stream) {
  const float* A  = (const float*)d_in[0];
  const float* x  = (const float*)d_in[1];
  const float* W1 = (const float*)d_in[2];
  const float* b1 = (const float*)d_in[3];
  const float* W2 = (const float*)d_in[4];
  const float* b2 = (const float*)d_in[5];
  float* out = (float*)d_out;

  char* ws = (char*)d_ws;
  size_t off = 0;
  auto alloc = [&](size_t bytes) {
    char* p = ws + off;
    off += (bytes + 255) & ~(size_t)255;
    return p;
  };

  unsigned int* deg_part = (unsigned int*)alloc((size_t)NPART * N * 4);
  float* dinv       = (float*)alloc((size_t)N * 4);
  float* s          = (float*)alloc((size_t)N * 4);
  float* s_part     = (float*)alloc((size_t)PCH * N * 4);
  float* z          = (float*)alloc((size_t)N * HID * 4);
  float* wz         = (float*)alloc((size_t)N * HID * 4);
  float* u_part     = (float*)alloc(64 * 16 * 4);
  float* t_part     = (float*)alloc((size_t)RCHUNK * N * HID * 4);
  unsigned long long* maskT = (unsigned long long*)alloc((size_t)N * NWORDS * 8);
  bool use_mask = (ws_size >= off);   // ~55 MB needed for the mask path

  k_xw1<<<N * HID / 256, 256, 0, stream>>>(x, W1, z);
  if (use_mask) {
    k_mask_deg<<<dim3(64, RY), 256, 0, stream>>>(A, maskT, deg_part);
    k_dinv_wz<<<N / 256, 256, 0, stream>>>(deg_part, NPART, z, dinv, wz);
    k_rowsum_T<<<512, 256, 0, stream>>>(maskT, dinv, s_part);
    k_spmm_T<<<dim3(64, RCHUNK), 256, 0, stream>>>(maskT, wz, t_part);
    k_combine<<<64, 256, 0, stream>>>(t_part, z, dinv, s_part, b1, u_part, 1);
  } else {
    hipMemsetAsync(deg_part, 0, (size_t)N * 4, stream);
    k_deg_only<<<dim3(64, 32), 256, 0, stream>>>(A, deg_part);
    k_dinv_wz<<<N / 256, 256, 0, stream>>>(deg_part, 1, z, dinv, wz);
    k_rowsum_direct<<<N / 4, 256, 0, stream>>>(A, dinv, s);
    k_spmm_direct<<<dim3(64, RCHUNK), 256, 0, stream>>>(A, wz, t_part);
    k_combine<<<64, 256, 0, stream>>>(t_part, z, dinv, s, b1, u_part, 0);
  }
  k_final<<<1, 64, 0, stream>>>(u_part, W2, b2, out);
}